// Round 1
// baseline (95.771 us; speedup 1.0000x reference)
//
#include <hip/hip_runtime.h>

#define IN_F 4096
#define OUT_F 11008
#define M 8
#define NWAVE 4                 // waves per block
#define KPW (IN_F / NWAVE)      // 1024 k-values per wave
#define STEPS (KPW / 32)        // 32 MFMA K-steps per wave

typedef __bf16 bf16x8 __attribute__((ext_vector_type(8)));
typedef float  f32x4  __attribute__((ext_vector_type(4)));

// Single fused kernel: out[r][j] = bias[j] + s_j * sum_k (w[k][j] - z_j) * bf16(x[r][k])
//
// - z_j folded into the B fragment (per-lane constant), so no rowsum pass,
//   no partials buffer, no reduce kernel, no workspace at all.
// - MFMA 16x16x32 bf16, layouts m89/m91-verified:
//   A[m=lane&15][k=quad*8+j], B[k=quad*8+j][n=lane&15], D[row=quad*4+reg][col=lane&15].
//   B-frag k-run of 8 == nibbles of ONE qweight int32 (LSB-first).
// - A pad rows 8..15 alias rows 0..7 (t&7): their D rows land in quads 2,3 and are
//   discarded, so no exec-masking; same-line loads dedup in the coalescer.
__global__ __launch_bounds__(256, 4) void gptq_fused_kernel(
    const int*   __restrict__ qw,    // (512, OUT_F)
    const float* __restrict__ x,     // (8, IN_F)
    const int*   __restrict__ qz,    // (1, OUT_F/8)
    const float* __restrict__ sc,    // (1, OUT_F)
    const float* __restrict__ bias,  // (OUT_F)
    float*       __restrict__ out)   // (8, OUT_F)
{
    __shared__ float red[NWAVE][M][16];   // 2 KB

    // XCD-contiguous column tiles: 688 blocks, 688 % 8 == 0 -> bijective swizzle.
    // Adjacent 16-col tiles (sharing a 128B qweight line) land on the same XCD L2.
    const int bid  = (int)blockIdx.x;
    const int cpx  = (int)gridDim.x >> 3;            // 86
    const int tile = (bid & 7) * cpx + (bid >> 3);

    const int lane = (int)threadIdx.x & 63;
    const int w    = (int)threadIdx.x >> 6;          // wave 0..3 = K-slice
    const int t    = lane & 15;                      // = m (A) = n (B) = col (D)
    const int quad = lane >> 4;                      // 0..3
    const int col  = tile * 16 + t;
    const int k0   = w * KPW;

    // zero point for this column (per-lane constant), +1 per GPTQ convention
    const float zf = (float)(((qz[col >> 3] >> ((col & 7) * 4)) & 15) + 1);

    // Prefetch the wave's entire qweight strip: 32 dword loads in flight,
    // HBM latency paid once; saddr-form loads keep VGPR cost at 1 each.
    int qv[STEPS];
    const int* qp = qw + (size_t)(k0 / 8 + quad) * OUT_F + col;
#pragma unroll
    for (int s = 0; s < STEPS; ++s)
        qv[s] = qp[(size_t)s * 4 * OUT_F];

    // A source: row t&7 (pad rows duplicate real rows; D rows 8..15 discarded).
    // In-loop offsets s*32 floats = 128 B fit the 13-bit signed global imm.
    const float* xp = x + (size_t)(t & 7) * IN_F + k0 + quad * 8;

    f32x4 acc = {0.f, 0.f, 0.f, 0.f};

#pragma unroll
    for (int s = 0; s < STEPS; ++s) {
        // ---- A fragment: bf16 truncation of x (matches prior numerics) ----
        union { unsigned int u[4]; bf16x8 v; } a;
        const float4 v0 = *(const float4*)(xp + s * 32);
        const float4 v1 = *(const float4*)(xp + s * 32 + 4);
        a.u[0] = (__float_as_uint(v0.x) >> 16) | (__float_as_uint(v0.y) & 0xffff0000u);
        a.u[1] = (__float_as_uint(v0.z) >> 16) | (__float_as_uint(v0.w) & 0xffff0000u);
        a.u[2] = (__float_as_uint(v1.x) >> 16) | (__float_as_uint(v1.y) & 0xffff0000u);
        a.u[3] = (__float_as_uint(v1.z) >> 16) | (__float_as_uint(v1.w) & 0xffff0000u);

        // ---- B fragment: (w - z), exact in bf16 (ints in [-16,14]) ----
        // Byte-spread nibbles so the compiler emits v_cvt_f32_ubyte0..3.
        const unsigned q  = (unsigned)qv[s];
        const unsigned lo = q & 0x0f0f0f0fu;         // nibbles 0,2,4,6 -> bytes 0..3
        const unsigned hi = (q >> 4) & 0x0f0f0f0fu;  // nibbles 1,3,5,7 -> bytes 0..3
        union { unsigned int u[4]; bf16x8 v; } b;
#pragma unroll
        for (int p = 0; p < 4; ++p) {
            const float f0 = (float)((lo >> (8 * p)) & 0xffu) - zf;  // k elem 2p
            const float f1 = (float)((hi >> (8 * p)) & 0xffu) - zf;  // k elem 2p+1
            b.u[p] = (__float_as_uint(f0) >> 16) | (__float_as_uint(f1) & 0xffff0000u);
        }

        acc = __builtin_amdgcn_mfma_f32_16x16x32_bf16(a.v, b.v, acc, 0, 0, 0);
    }

    // D rows 0..7 (quads 0,1) are the real x-rows; stash per-wave partials in LDS.
    if (quad < 2) {
#pragma unroll
        for (int r = 0; r < 4; ++r)
            red[w][quad * 4 + r][t] = acc[r];   // 2-way bank alias only (free)
    }
    __syncthreads();

    // Cross-wave K-reduction + fused scale/bias epilogue: 128 threads, one output each.
    if (threadIdx.x < M * 16) {
        const int r = (int)threadIdx.x >> 4;
        const int c = (int)threadIdx.x & 15;
        float sacc = 0.f;
#pragma unroll
        for (int i = 0; i < NWAVE; ++i) sacc += red[i][r][c];
        const int j = tile * 16 + c;
        out[(size_t)r * OUT_F + j] = fmaf(sc[j], sacc, bias[j]);
    }
}

extern "C" void kernel_launch(void* const* d_in, const int* in_sizes, int n_in,
                              void* d_out, int out_size, void* d_ws, size_t ws_size,
                              hipStream_t stream) {
    const float* x    = (const float*)d_in[0];
    const int*   qw   = (const int*)d_in[1];
    const int*   qz   = (const int*)d_in[2];
    const float* sc   = (const float*)d_in[3];
    const float* bias = (const float*)d_in[4];

    hipLaunchKernelGGL(gptq_fused_kernel, dim3(OUT_F / 16), dim3(256), 0, stream,
                       qw, x, qz, sc, bias, (float*)d_out);
}

// Round 2
// 94.801 us; speedup vs baseline: 1.0102x; 1.0102x over previous
//
#include <hip/hip_runtime.h>

#define IN_F 4096
#define OUT_F 11008
#define M 8
#define NWAVE 4                 // waves per block
#define KPW (IN_F / NWAVE)      // 1024 k-values per wave
#define STEPS (KPW / 32)        // 32 MFMA K-steps per wave
#define CHUNK 8                 // prefetch depth (qweight dwords in flight)
#define NCHUNK (STEPS / CHUNK)  // 4

typedef __bf16 bf16x8 __attribute__((ext_vector_type(8)));
typedef float  f32x4  __attribute__((ext_vector_type(4)));

// Single fused kernel: out[r][j] = bias[j] + s_j * sum_k (w[k][j] - z_j) * bf16(x[r][k])
//
// - z_j folded into the B fragment (per-lane constant): no rowsum pass, no
//   partials buffer, no reduce kernel, zero workspace use.
// - MFMA 16x16x32 bf16, layouts m89/m91-verified:
//   A[m=lane&15][k=quad*8+j], B[k=quad*8+j][n=lane&15], D[row=quad*4+reg][col=lane&15].
//   B-frag k-run of 8 == nibbles of ONE qweight int32 (LSB-first).
// - A pad rows 8..15 alias rows 0..7 (t&7): their D rows land in quads 2,3 and
//   are discarded; duplicate loads dedup in cache.
// - qweight prefetch is software-pipelined in CHUNK=8 dword chunks with two
//   NAMED arrays (all indices compile-time after unroll -> registers, no
//   scratch; round-1's 32-deep prefetch spilled under the 128-VGPR cap).
__global__ __launch_bounds__(256, 4) void gptq_fused_kernel(
    const int*   __restrict__ qw,    // (512, OUT_F)
    const float* __restrict__ x,     // (8, IN_F)
    const int*   __restrict__ qz,    // (1, OUT_F/8)
    const float* __restrict__ sc,    // (1, OUT_F)
    const float* __restrict__ bias,  // (OUT_F)
    float*       __restrict__ out)   // (8, OUT_F)
{
    __shared__ float red[NWAVE][M][16];   // 2 KB

    // XCD-contiguous column tiles: 688 % 8 == 0 -> bijective swizzle. HW maps
    // block b to XCD b%8; tile=(b&7)*86+(b>>3) gives each XCD a contiguous
    // 86-tile range, so adjacent tiles sharing a 128B qweight line stay on one L2.
    const int bid  = (int)blockIdx.x;
    const int cpx  = (int)gridDim.x >> 3;            // 86
    const int tile = (bid & 7) * cpx + (bid >> 3);

    const int lane = (int)threadIdx.x & 63;
    const int w    = (int)threadIdx.x >> 6;          // wave 0..3 = K-slice
    const int t    = lane & 15;                      // = m (A) = n (B) = col (D)
    const int quad = lane >> 4;                      // 0..3
    const int col  = tile * 16 + t;
    const int k0   = w * KPW;

    // zero point for this column (per-lane constant), +1 per GPTQ convention
    const float zf = (float)(((qz[col >> 3] >> ((col & 7) * 4)) & 15) + 1);

    const int* qp = qw + (size_t)(k0 / 8 + quad) * OUT_F + col;
    // A source: row t&7; in-loop byte offsets s*128 (+16) stay within the
    // 13-bit signed global imm for s<32.
    const float* xp = x + (size_t)(t & 7) * IN_F + k0 + quad * 8;

    f32x4 acc = {0.f, 0.f, 0.f, 0.f};

    auto loadq = [&](int (&dst)[CHUNK], int c) {
#pragma unroll
        for (int s = 0; s < CHUNK; ++s)
            dst[s] = qp[(size_t)(c * CHUNK + s) * 4 * OUT_F];
    };
    auto compute = [&](const int (&q)[CHUNK], int c) {
#pragma unroll
        for (int s = 0; s < CHUNK; ++s) {
            const int ks = c * CHUNK + s;
            // ---- A fragment: bf16 truncation of x ----
            union { unsigned int u[4]; bf16x8 v; } a;
            const float4 v0 = *(const float4*)(xp + ks * 32);
            const float4 v1 = *(const float4*)(xp + ks * 32 + 4);
            a.u[0] = (__float_as_uint(v0.x) >> 16) | (__float_as_uint(v0.y) & 0xffff0000u);
            a.u[1] = (__float_as_uint(v0.z) >> 16) | (__float_as_uint(v0.w) & 0xffff0000u);
            a.u[2] = (__float_as_uint(v1.x) >> 16) | (__float_as_uint(v1.y) & 0xffff0000u);
            a.u[3] = (__float_as_uint(v1.z) >> 16) | (__float_as_uint(v1.w) & 0xffff0000u);

            // ---- B fragment: (w - z), exact in bf16 (ints in [-16,14]) ----
            // Byte-spread nibbles -> v_cvt_f32_ubyte0..3 extracts bytes for free.
            const unsigned qq = (unsigned)q[s];
            const unsigned lo = qq & 0x0f0f0f0fu;         // nibbles 0,2,4,6
            const unsigned hi = (qq >> 4) & 0x0f0f0f0fu;  // nibbles 1,3,5,7
            union { unsigned int u[4]; bf16x8 v; } b;
#pragma unroll
            for (int p = 0; p < 4; ++p) {
                const float f0 = (float)((lo >> (8 * p)) & 0xffu) - zf;  // k elem 2p
                const float f1 = (float)((hi >> (8 * p)) & 0xffu) - zf;  // k elem 2p+1
                b.u[p] = (__float_as_uint(f0) >> 16) | (__float_as_uint(f1) & 0xffff0000u);
            }

            acc = __builtin_amdgcn_mfma_f32_16x16x32_bf16(a.v, b.v, acc, 0, 0, 0);
        }
    };

    // 2-stage pipeline over 4 chunks: prefetch c+1 while computing c.
    int q0[CHUNK], q1[CHUNK];
    loadq(q0, 0);
    loadq(q1, 1);
    compute(q0, 0);
    loadq(q0, 2);
    compute(q1, 1);
    loadq(q1, 3);
    compute(q0, 2);
    compute(q1, 3);

    // D rows 0..7 (quads 0,1) are the real x-rows; per-wave partials via LDS.
    if (quad < 2) {
#pragma unroll
        for (int r = 0; r < 4; ++r)
            red[w][quad * 4 + r][t] = acc[r];   // 2-way bank alias only (free)
    }
    __syncthreads();

    // Cross-wave K-reduction + fused scale/bias epilogue: 128 threads, 1 output each.
    if (threadIdx.x < M * 16) {
        const int r = (int)threadIdx.x >> 4;
        const int c = (int)threadIdx.x & 15;
        float sacc = 0.f;
#pragma unroll
        for (int i = 0; i < NWAVE; ++i) sacc += red[i][r][c];
        const int j = tile * 16 + c;
        out[(size_t)r * OUT_F + j] = fmaf(sc[j], sacc, bias[j]);
    }
}

extern "C" void kernel_launch(void* const* d_in, const int* in_sizes, int n_in,
                              void* d_out, int out_size, void* d_ws, size_t ws_size,
                              hipStream_t stream) {
    const float* x    = (const float*)d_in[0];
    const int*   qw   = (const int*)d_in[1];
    const int*   qz   = (const int*)d_in[2];
    const float* sc   = (const float*)d_in[3];
    const float* bias = (const float*)d_in[4];

    hipLaunchKernelGGL(gptq_fused_kernel, dim3(OUT_F / 16), dim3(256), 0, stream,
                       qw, x, qz, sc, bias, (float*)d_out);
}